// Round 2
// baseline (243.829 us; speedup 1.0000x reference)
//
#include <hip/hip_runtime.h>
#include <hip/hip_bf16.h>

#define B_   8
#define N_   2048
#define FIN  128
#define OUTD 256
#define H_   4
#define LOG2E 1.44269504088896340736f

typedef __bf16 bf16x8 __attribute__((ext_vector_type(8)));
typedef float  f32x4  __attribute__((ext_vector_type(4)));
typedef unsigned short u16x8 __attribute__((ext_vector_type(8)));

__device__ __forceinline__ bf16x8 to_bf16x8(float4 a, float4 b) {
    u16x8 u;
    __hip_bfloat16 t;
    t = __float2bfloat16(a.x); u[0] = *(unsigned short*)&t;
    t = __float2bfloat16(a.y); u[1] = *(unsigned short*)&t;
    t = __float2bfloat16(a.z); u[2] = *(unsigned short*)&t;
    t = __float2bfloat16(a.w); u[3] = *(unsigned short*)&t;
    t = __float2bfloat16(b.x); u[4] = *(unsigned short*)&t;
    t = __float2bfloat16(b.y); u[5] = *(unsigned short*)&t;
    t = __float2bfloat16(b.z); u[6] = *(unsigned short*)&t;
    t = __float2bfloat16(b.w); u[7] = *(unsigned short*)&t;
    return __builtin_bit_cast(bf16x8, u);
}

// ---------------- kernel 1: fused  Xt = X@W.T (bf16 MFMA)  +  s,t logits ------------
// grid (4, 1024): blockIdx.x = head h, blockIdx.y = 16-row tile. Block = 4 waves,
// wave w covers channel tile c0 = h*64 + w*16  -> block covers ALL 64 channels of
// head h for its 16 rows => s,t finish in-block (shfl + tiny LDS reduce, no atomics).
// A-frag: A[m=lane&15][k=q*8+j]; B-frag from W rows (B[k][n]=W[n][k]).
// C/D: col=lane&15, row=q*4+reg (verified m89/m91).
__global__ __launch_bounds__(256) void gemm_st(const float* __restrict__ X,
                                               const float* __restrict__ W,
                                               const float* __restrict__ a_src,
                                               const float* __restrict__ a_dst,
                                               float* __restrict__ Xt,
                                               float* __restrict__ s_arr,
                                               float* __restrict__ t_arr) {
    __shared__ float redS[4][4][4];   // [wave][q][reg]
    __shared__ float redT[4][4][4];

    const int h    = blockIdx.x;
    const int r0   = blockIdx.y * 16;
    const int wave = threadIdx.x >> 6;
    const int lane = threadIdx.x & 63;
    const int m = lane & 15, q = lane >> 4;
    const int c0 = h * 64 + wave * 16;

    const float4* Xrow = (const float4*)(X + (size_t)(r0 + m) * FIN);
    const float4* Wrow = (const float4*)(W + (size_t)(c0 + m) * FIN);

    f32x4 acc = {0.f, 0.f, 0.f, 0.f};
#pragma unroll
    for (int kc = 0; kc < 4; ++kc) {            // K = 128 = 4 x 32
        bf16x8 af = to_bf16x8(Xrow[kc * 8 + 2 * q], Xrow[kc * 8 + 2 * q + 1]);
        bf16x8 bf = to_bf16x8(Wrow[kc * 8 + 2 * q], Wrow[kc * 8 + 2 * q + 1]);
        acc = __builtin_amdgcn_mfma_f32_16x16x32_bf16(af, bf, acc, 0, 0, 0);
    }

    // store Xt tile
    float* outp = Xt + (size_t)(r0 + q * 4) * OUTD + c0 + m;
#pragma unroll
    for (int reg = 0; reg < 4; ++reg)
        outp[(size_t)reg * OUTD] = acc[reg];

    // partial s,t over this wave's 16 channels; reduce across m (lane bits 0-3)
    const int ch = wave * 16 + m;               // channel within head
    float as = a_src[h * 64 + ch];
    float ad = a_dst[h * 64 + ch];
    float ps[4], pt[4];
#pragma unroll
    for (int reg = 0; reg < 4; ++reg) {
        ps[reg] = acc[reg] * as;
        pt[reg] = acc[reg] * ad;
#pragma unroll
        for (int mk = 1; mk < 16; mk <<= 1) {
            ps[reg] += __shfl_xor(ps[reg], mk);
            pt[reg] += __shfl_xor(pt[reg], mk);
        }
    }
    if (m == 0) {
#pragma unroll
        for (int reg = 0; reg < 4; ++reg) {
            redS[wave][q][reg] = ps[reg];
            redT[wave][q][reg] = pt[reg];
        }
    }
    __syncthreads();
    if (threadIdx.x < 16) {
        int rr = threadIdx.x;                   // row within tile = q*4+reg
        int qq = rr >> 2, reg = rr & 3;
        float s = redS[0][qq][reg] + redS[1][qq][reg] + redS[2][qq][reg] + redS[3][qq][reg];
        float t = redT[0][qq][reg] + redT[1][qq][reg] + redT[2][qq][reg] + redT[3][qq][reg];
        size_t row = (size_t)r0 + rr;
        s_arr[row * H_ + h] = s * LOG2E;        // pre-scale: exp2 in main kernel
        t_arr[row * H_ + h] = t * LOG2E;
    }
}

// ---------------- kernel 2: masked-softmax diagonal + output scale ----------------
// grid 1024 (8 graphs x 128 row-tiles), block 256: 16 rows/block, 16 lanes per row.
// LDS: t' as SoA head-planes t_pl[h][j] (32 KB) -> b128 reads over 4 consecutive j:
// lane stride 16 B = 2-way bank alias = free (m136); 4 row-groups broadcast.
__global__ __launch_bounds__(256) void gat_main(const float* __restrict__ A,
                                                const float* __restrict__ s_arr,
                                                const float* __restrict__ t_arr,
                                                float* __restrict__ out) {
    __shared__ float t_pl[H_][N_];              // 32 KB
    __shared__ float diag_lds[16][H_];

    const int b  = blockIdx.x >> 7;
    const int rt = blockIdx.x & 127;
    const int r0 = rt * 16;
    const int tid = threadIdx.x;

    // stage t' for graph b, transposing [j][h] -> [h][j]
    const f32x4* tsrc = (const f32x4*)(t_arr + (size_t)b * N_ * H_);
    for (int i = tid; i < N_; i += 256) {
        f32x4 tv = tsrc[i];
        t_pl[0][i] = tv[0];
        t_pl[1][i] = tv[1];
        t_pl[2][i] = tv[2];
        t_pl[3][i] = tv[3];
    }
    __syncthreads();

    const int r  = tid >> 4;                    // row within tile
    const int lj = tid & 15;                    // 16 lanes sweep j
    const int gi = r0 + r;

    f32x4 s4 = *(const f32x4*)(s_arr + ((size_t)b * N_ + gi) * H_);
    const float* Arow = A + ((size_t)b * N_ + gi) * N_;

    float acc0 = 0.f, acc1 = 0.f, acc2 = 0.f, acc3 = 0.f;
    for (int it = 0; it < N_ / 64; ++it) {
        const int j0 = it * 64 + lj * 4;
        f32x4 a4 = *(const f32x4*)(Arow + j0);
        f32x4 t0 = *(const f32x4*)&t_pl[0][j0];
        f32x4 t1 = *(const f32x4*)&t_pl[1][j0];
        f32x4 t2 = *(const f32x4*)&t_pl[2][j0];
        f32x4 t3 = *(const f32x4*)&t_pl[3][j0];
#pragma unroll
        for (int jj = 0; jj < 4; ++jj) {
            float aj = a4[jj];
            float y0 = s4[0] + t0[jj]; y0 = fmaxf(y0, 0.2f * y0); acc0 = fmaf(aj, exp2f(y0), acc0);
            float y1 = s4[1] + t1[jj]; y1 = fmaxf(y1, 0.2f * y1); acc1 = fmaf(aj, exp2f(y1), acc1);
            float y2 = s4[2] + t2[jj]; y2 = fmaxf(y2, 0.2f * y2); acc2 = fmaf(aj, exp2f(y2), acc2);
            float y3 = s4[3] + t3[jj]; y3 = fmaxf(y3, 0.2f * y3); acc3 = fmaf(aj, exp2f(y3), acc3);
        }
    }
    // reduce across the 16 lanes of this row
#pragma unroll
    for (int mk = 8; mk > 0; mk >>= 1) {
        acc0 += __shfl_xor(acc0, mk);
        acc1 += __shfl_xor(acc1, mk);
        acc2 += __shfl_xor(acc2, mk);
        acc3 += __shfl_xor(acc3, mk);
    }
    if (lj == 0) {
        float y, e;
        y = s4[0] + t_pl[0][gi]; y = fmaxf(y, 0.2f * y); e = exp2f(y); diag_lds[r][0] = e / acc0;
        y = s4[1] + t_pl[1][gi]; y = fmaxf(y, 0.2f * y); e = exp2f(y); diag_lds[r][1] = e / acc1;
        y = s4[2] + t_pl[2][gi]; y = fmaxf(y, 0.2f * y); e = exp2f(y); diag_lds[r][2] = e / acc2;
        y = s4[3] + t_pl[3][gi]; y = fmaxf(y, 0.2f * y); e = exp2f(y); diag_lds[r][3] = e / acc3;
    }
    __syncthreads();

    // epilogue: out = diag * X_trans (in place; X_trans lives in d_out)
    float* orow = out + ((size_t)b * N_ + gi) * OUTD;
#pragma unroll
    for (int ii = 0; ii < 4; ++ii) {
        int c = lj * 4 + ii * 64;               // head h == ii (lj*4 < 64)
        float4 v = *(float4*)(orow + c);
        float dg = diag_lds[r][ii];
        v.x *= dg; v.y *= dg; v.z *= dg; v.w *= dg;
        *(float4*)(orow + c) = v;
    }
}

extern "C" void kernel_launch(void* const* d_in, const int* in_sizes, int n_in,
                              void* d_out, int out_size, void* d_ws, size_t ws_size,
                              hipStream_t stream) {
    const float* A     = (const float*)d_in[0];
    const float* X     = (const float*)d_in[1];
    const float* W     = (const float*)d_in[2];
    const float* a_src = (const float*)d_in[3];
    const float* a_dst = (const float*)d_in[4];
    float* out = (float*)d_out;

    char* ws = (char*)d_ws;
    float* s_arr = (float*)ws;                   // 262,144 B
    float* t_arr = (float*)(ws + 262144);        // 262,144 B

    // 1) fused: Xt = X@W.T (bf16 MFMA, written into d_out) + s,t logits
    gemm_st<<<dim3(4, 1024), 256, 0, stream>>>(X, W, a_src, a_dst, out, s_arr, t_arr);
    // 2) masked softmax diagonal + in-place scale
    gat_main<<<1024, 256, 0, stream>>>(A, s_arr, t_arr, out);
}